// Round 1
// baseline (38.256 us; speedup 1.0000x reference)
//
#include <hip/hip_runtime.h>

#define B_SZ   256
#define T_SZ   512
#define EMB    128
#define HID    256
#define NCLS   32000

typedef __attribute__((ext_vector_type(8))) short short8;
typedef __attribute__((ext_vector_type(4))) float f32x4;

__device__ inline unsigned short bf16rne(float f) {
    union { float f; unsigned int u; } v; v.f = f;
    unsigned int u = v.u;
    u += 0x7FFFu + ((u >> 16) & 1u);   // round-to-nearest-even
    return (unsigned short)(u >> 16);
}

// ---------------------------------------------------------------------------
// Kernel 1: h_last[b][k] = o0 * tanh(i0 * g0) for the LAST timestep only.
// 64 blocks x 256 threads; each block handles 4 batch rows, thread = one k.
// Output: bf16 row-major [256][256] into d_ws.
// ---------------------------------------------------------------------------
__global__ __launch_bounds__(256)
void lstm_h_last(const int* __restrict__ X, const float* __restrict__ C_table,
                 const float* __restrict__ U_i, const float* __restrict__ b_i,
                 const float* __restrict__ U_c, const float* __restrict__ b_c,
                 const float* __restrict__ U_o, const float* __restrict__ b_o,
                 unsigned short* __restrict__ hws) {
    __shared__ float e[4][EMB];
    __shared__ int idx[4];
    const int t  = threadIdx.x;          // 0..255
    const int b4 = blockIdx.x * 4;

    if (t < 4) idx[t] = X[(size_t)(b4 + t) * T_SZ + (T_SZ - 1)];
    __syncthreads();

    // load 4 embedding rows (4*128 = 512 floats, 256 threads -> 2 each)
    #pragma unroll
    for (int p = 0; p < 2; ++p) {
        int lin  = p * 256 + t;
        int r    = lin >> 7;
        int ei   = lin & 127;
        e[r][ei] = C_table[(size_t)idx[r] * EMB + ei];
    }
    __syncthreads();

    const int k = t;  // hidden index
    float ai[4] = {0.f, 0.f, 0.f, 0.f};
    float ac[4] = {0.f, 0.f, 0.f, 0.f};
    float ao[4] = {0.f, 0.f, 0.f, 0.f};

    for (int ee = 0; ee < EMB; ++ee) {
        float ui = U_i[ee * HID + k];
        float uc = U_c[ee * HID + k];
        float uo = U_o[ee * HID + k];
        #pragma unroll
        for (int r = 0; r < 4; ++r) {
            float ev = e[r][ee];
            ai[r] += ev * ui;
            ac[r] += ev * uc;
            ao[r] += ev * uo;
        }
    }

    const float bi = b_i[k], bc = b_c[k], bo = b_o[k];
    #pragma unroll
    for (int r = 0; r < 4; ++r) {
        float i0 = 1.f / (1.f + expf(-(ai[r] + bi)));
        float g0 = tanhf(ac[r] + bc);
        float o0 = 1.f / (1.f + expf(-(ao[r] + bo)));
        float c0 = i0 * g0;
        float h  = o0 * tanhf(c0);
        hws[(size_t)(b4 + r) * HID + k] = bf16rne(h);
    }
}

// ---------------------------------------------------------------------------
// Kernel 2: logits[m][n] = sum_k h[m][k] * W_w[n][k] + b_out[n]
// M=256 N=32000 K=256.  Grid = 500 blocks (BN=64), 512 threads = 8 waves.
// Each wave owns 32 M-rows x all 64 N-cols (2 x 4 fragments of 16x16).
// W tile staged f32 -> bf16 in LDS, rows padded to 264 bf16 (528B) to break
// the 16-way bank conflict on column-slice ds_read_b128 (stride 132 dwords
// == 4 mod 32 -> 2-way max, free).
// ---------------------------------------------------------------------------
#define BN      64
#define LDS_ROW 264   // bf16 elements per padded row (528 bytes)

__global__ __launch_bounds__(512)
void logits_gemm(const unsigned short* __restrict__ hws,
                 const float* __restrict__ Ww,
                 const float* __restrict__ b_out,
                 float* __restrict__ out) {
    __shared__ unsigned short Bs[BN * LDS_ROW];

    const int t    = threadIdx.x;        // 0..511
    const int n0   = blockIdx.x * BN;
    const int wid  = t >> 6;             // 0..7
    const int lane = t & 63;
    const int l15  = lane & 15;
    const int lq   = lane >> 4;          // 0..3

    // ---- stage W_w[n0 .. n0+63][0..255] as bf16 into LDS ----
    // 64 rows x 64 float4 = 4096 float4; 512 threads x 8 each, coalesced.
    #pragma unroll
    for (int it = 0; it < 8; ++it) {
        int lin = it * 512 + t;
        int row = lin >> 6;              // 0..63
        int c4  = lin & 63;              // float4 index in row
        float4 w = *reinterpret_cast<const float4*>(
            Ww + (size_t)(n0 + row) * HID + (c4 << 2));
        uint2 pk;
        pk.x = ((unsigned)bf16rne(w.y) << 16) | bf16rne(w.x);
        pk.y = ((unsigned)bf16rne(w.w) << 16) | bf16rne(w.z);
        *reinterpret_cast<uint2*>(
            reinterpret_cast<char*>(Bs) + row * (LDS_ROW * 2) + (c4 << 3)) = pk;
    }
    __syncthreads();

    // ---- K-loop: 8 steps of K=32, mfma_f32_16x16x32_bf16 ----
    f32x4 acc[2][4] = {};
    const int rowA_base = wid * 32;

    for (int ks = 0; ks < 8; ++ks) {
        const int k0 = ks * 32;
        short8 a[2], b[4];
        #pragma unroll
        for (int i = 0; i < 2; ++i) {
            a[i] = *reinterpret_cast<const short8*>(
                hws + (size_t)(rowA_base + i * 16 + l15) * HID + k0 + lq * 8);
        }
        #pragma unroll
        for (int j = 0; j < 4; ++j) {
            int rowB = j * 16 + l15;
            b[j] = *reinterpret_cast<const short8*>(
                reinterpret_cast<const char*>(Bs) + rowB * (LDS_ROW * 2) +
                ((k0 + lq * 8) << 1));
        }
        #pragma unroll
        for (int i = 0; i < 2; ++i)
            #pragma unroll
            for (int j = 0; j < 4; ++j)
                acc[i][j] = __builtin_amdgcn_mfma_f32_16x16x32_bf16(
                    a[i], b[j], acc[i][j], 0, 0, 0);
    }

    // ---- epilogue: C/D layout col = lane&15, row = (lane>>4)*4 + reg ----
    #pragma unroll
    for (int j = 0; j < 4; ++j) {
        int col = n0 + j * 16 + l15;
        float bias = b_out[col];
        #pragma unroll
        for (int i = 0; i < 2; ++i) {
            int row0 = rowA_base + i * 16 + lq * 4;
            #pragma unroll
            for (int tt = 0; tt < 4; ++tt)
                out[(size_t)(row0 + tt) * NCLS + col] = acc[i][j][tt] + bias;
        }
    }
}

// ---------------------------------------------------------------------------
extern "C" void kernel_launch(void* const* d_in, const int* in_sizes, int n_in,
                              void* d_out, int out_size, void* d_ws, size_t ws_size,
                              hipStream_t stream) {
    const int*   X       = (const int*)  d_in[0];
    const float* C_table = (const float*)d_in[1];
    const float* U_i     = (const float*)d_in[2];
    const float* b_i     = (const float*)d_in[4];
    const float* U_c     = (const float*)d_in[8];
    const float* b_c     = (const float*)d_in[10];
    const float* U_o     = (const float*)d_in[11];
    const float* b_o     = (const float*)d_in[13];
    const float* W_w     = (const float*)d_in[26];
    const float* b_out   = (const float*)d_in[27];
    float* out = (float*)d_out;

    unsigned short* hws = (unsigned short*)d_ws;  // bf16 h_last [256][256]

    lstm_h_last<<<B_SZ / 4, 256, 0, stream>>>(X, C_table, U_i, b_i, U_c, b_c,
                                              U_o, b_o, hws);
    logits_gemm<<<NCLS / BN, 512, 0, stream>>>(hws, W_w, b_out, out);
}